// Round 1
// baseline (431.087 us; speedup 1.0000x reference)
//
#include <hip/hip_runtime.h>
#include <math.h>

#define NN 10000
#define EE 160000
#define ET 170000
#define FIN 256
#define HH 8
#define CC 64
#define HC 512
#define NCLS 40

// ---------- CSR construction ----------
__global__ __launch_bounds__(256) void zero_int(int* p, int n) {
    int i = blockIdx.x * 256 + threadIdx.x;
    if (i < n) p[i] = 0;
}

__global__ __launch_bounds__(256) void hist_kernel(const int* __restrict__ ei,
                                                   int* __restrict__ deg) {
    int e = blockIdx.x * 256 + threadIdx.x;
    if (e >= ET) return;
    int d = (e < EE) ? ei[EE + e] : (e - EE);   // self-loops appended
    atomicAdd(&deg[d], 1);
}

// single-block exclusive scan over N=10000 degrees -> off[N+1], cursor copy
__global__ __launch_bounds__(1024) void scan_kernel(const int* __restrict__ deg,
                                                    int* __restrict__ off,
                                                    int* __restrict__ cursor) {
    __shared__ int sh[1024];
    int t = threadIdx.x;
    const int CH = 10;                      // ceil(10000/1024)
    int base = t * CH;
    int loc[CH];
    int sum = 0;
#pragma unroll
    for (int j = 0; j < CH; ++j) {
        int idx = base + j;
        int v = (idx < NN) ? deg[idx] : 0;
        loc[j] = sum;
        sum += v;
    }
    sh[t] = sum;
    __syncthreads();
    for (int ofs = 1; ofs < 1024; ofs <<= 1) {
        int v = (t >= ofs) ? sh[t - ofs] : 0;
        __syncthreads();
        sh[t] += v;
        __syncthreads();
    }
    int excl = sh[t] - sum;
#pragma unroll
    for (int j = 0; j < CH; ++j) {
        int idx = base + j;
        if (idx < NN) {
            int o = excl + loc[j];
            off[idx] = o;
            cursor[idx] = o;
        }
    }
    if (t == 1023) off[NN] = sh[1023];
}

__global__ __launch_bounds__(256) void scatter_kernel(const int* __restrict__ ei,
                                                      int* __restrict__ cursor,
                                                      int* __restrict__ srcs) {
    int e = blockIdx.x * 256 + threadIdx.x;
    if (e >= ET) return;
    int s, d;
    if (e < EE) { s = ei[e]; d = ei[EE + e]; }
    else        { s = e - EE; d = s; }
    int pos = atomicAdd(&cursor[d], 1);
    srcs[pos] = s;
}

// ---------- tiled fp32 GEMM: C[M,Nc] = A[M,K] @ B[K,Nc] ----------
__global__ __launch_bounds__(256) void gemm_kernel(const float* __restrict__ A,
                                                   const float* __restrict__ B,
                                                   float* __restrict__ C,
                                                   int M, int K, int Nc) {
    __shared__ float As[16][64];   // [k][row] (transposed)
    __shared__ float Bs[16][64];   // [k][col]
    int tid = threadIdx.x;
    int bm = blockIdx.x * 64, bn = blockIdx.y * 64;
    int tx = tid & 15, ty = tid >> 4;
    int arow = tid >> 2, acol = (tid & 3) * 4;
    int brow = tid >> 4, bcol = (tid & 15) * 4;
    float acc[4][4] = {{0.f}};
    for (int k0 = 0; k0 < K; k0 += 16) {
        float4 av = make_float4(0.f, 0.f, 0.f, 0.f);
        int gr = bm + arow;
        if (gr < M) av = *(const float4*)(A + (size_t)gr * K + k0 + acol);
        As[acol + 0][arow] = av.x;
        As[acol + 1][arow] = av.y;
        As[acol + 2][arow] = av.z;
        As[acol + 3][arow] = av.w;

        float4 bv = make_float4(0.f, 0.f, 0.f, 0.f);
        int gc = bn + bcol;
        if (gc + 3 < Nc) {
            bv = *(const float4*)(B + (size_t)(k0 + brow) * Nc + gc);
        } else {
            const float* bp = B + (size_t)(k0 + brow) * Nc;
            if (gc     < Nc) bv.x = bp[gc];
            if (gc + 1 < Nc) bv.y = bp[gc + 1];
            if (gc + 2 < Nc) bv.z = bp[gc + 2];
        }
        *(float4*)&Bs[brow][bcol] = bv;
        __syncthreads();
#pragma unroll
        for (int kk = 0; kk < 16; ++kk) {
            float4 a = *(const float4*)&As[kk][ty * 4];
            float4 b = *(const float4*)&Bs[kk][tx * 4];
            acc[0][0] += a.x * b.x; acc[0][1] += a.x * b.y; acc[0][2] += a.x * b.z; acc[0][3] += a.x * b.w;
            acc[1][0] += a.y * b.x; acc[1][1] += a.y * b.y; acc[1][2] += a.y * b.z; acc[1][3] += a.y * b.w;
            acc[2][0] += a.z * b.x; acc[2][1] += a.z * b.y; acc[2][2] += a.z * b.z; acc[2][3] += a.z * b.w;
            acc[3][0] += a.w * b.x; acc[3][1] += a.w * b.y; acc[3][2] += a.w * b.z; acc[3][3] += a.w * b.w;
        }
        __syncthreads();
    }
#pragma unroll
    for (int i = 0; i < 4; ++i) {
        int r = bm + ty * 4 + i;
        if (r >= M) continue;
#pragma unroll
        for (int j = 0; j < 4; ++j) {
            int c2 = bn + tx * 4 + j;
            if (c2 < Nc) C[(size_t)r * Nc + c2] = acc[i][j];
        }
    }
}

// ---------- attention coefficients: al_s/al_d [N,H] ----------
__global__ __launch_bounds__(256) void attn_kernel(const float* __restrict__ hx,
                                                   const float* __restrict__ a_src,
                                                   const float* __restrict__ a_dst,
                                                   float* __restrict__ al_s,
                                                   float* __restrict__ al_d,
                                                   int Hh, int Cc) {
    int wave = threadIdx.x >> 6, lane = threadIdx.x & 63;
    int n = blockIdx.x * 4 + wave;
    if (n >= NN) return;
    for (int h = 0; h < Hh; ++h) {
        float vs = 0.f, vd = 0.f;
        if (lane < Cc) {
            float v = hx[((size_t)n * Hh + h) * Cc + lane];
            vs = v * a_src[h * Cc + lane];
            vd = v * a_dst[h * Cc + lane];
        }
#pragma unroll
        for (int o = 32; o; o >>= 1) {
            vs += __shfl_down(vs, o);
            vd += __shfl_down(vd, o);
        }
        if (lane == 0) {
            al_s[n * Hh + h] = vs;
            al_d[n * Hh + h] = vd;
        }
    }
}

// ---------- fused softmax+aggregate, layers 0/1 (H=8,C=64) ----------
// one block (256 thr) per dst node; thread covers 2 channels; denom fused.
__global__ __launch_bounds__(256) void aggregate_kernel(const float* __restrict__ hx,
                                                        const float* __restrict__ al_s,
                                                        const float* __restrict__ al_d,
                                                        const int* __restrict__ off,
                                                        const int* __restrict__ srcs,
                                                        const float* __restrict__ bias,
                                                        float* __restrict__ out,
                                                        int applyElu) {
    int n = blockIdx.x;
    int tid = threadIdx.x;
    int ch = tid * 2;
    int h = ch >> 6;
    float ald = al_d[n * HH + h];
    int i0 = off[n], i1 = off[n + 1];
    float a0 = 0.f, a1 = 0.f, den = 0.f;
    for (int i = i0; i < i1; ++i) {
        int s = srcs[i];
        float e = al_s[s * HH + h] + ald;
        e = e > 0.f ? e : 0.2f * e;           // leaky_relu
        float w = __expf(e);                  // no max-sub needed (tame logits)
        float2 v = *(const float2*)(hx + (size_t)s * HC + ch);
        a0 += w * v.x;
        a1 += w * v.y;
        den += w;
    }
    float inv = 1.f / (den + 1e-16f);
    float o0 = a0 * inv + bias[ch];
    float o1 = a1 * inv + bias[ch + 1];
    if (applyElu) {
        o0 = o0 > 0.f ? o0 : expm1f(o0);
        o1 = o1 > 0.f ? o1 : expm1f(o1);
    }
    out[(size_t)n * HC + ch]     = o0;
    out[(size_t)n * HC + ch + 1] = o1;
}

// ---------- layer 2 aggregate (H=1,C=40), no ELU ----------
__global__ __launch_bounds__(64) void aggregate2_kernel(const float* __restrict__ hx,
                                                        const float* __restrict__ al_s,
                                                        const float* __restrict__ al_d,
                                                        const int* __restrict__ off,
                                                        const int* __restrict__ srcs,
                                                        const float* __restrict__ bias,
                                                        float* __restrict__ out) {
    int n = blockIdx.x;
    int c = threadIdx.x;
    float ald = al_d[n];
    int i0 = off[n], i1 = off[n + 1];
    float acc = 0.f, den = 0.f;
    for (int i = i0; i < i1; ++i) {
        int s = srcs[i];
        float e = al_s[s] + ald;
        e = e > 0.f ? e : 0.2f * e;
        float w = __expf(e);
        if (c < NCLS) acc += w * hx[(size_t)s * NCLS + c];
        den += w;
    }
    if (c < NCLS) out[(size_t)n * NCLS + c] = acc / (den + 1e-16f) + bias[c];
}

extern "C" void kernel_launch(void* const* d_in, const int* in_sizes, int n_in,
                              void* d_out, int out_size, void* d_ws, size_t ws_size,
                              hipStream_t stream) {
    const float* x   = (const float*)d_in[0];
    const int*   ei  = (const int*)  d_in[1];
    const float* W0  = (const float*)d_in[2];
    const float* as0 = (const float*)d_in[3];
    const float* ad0 = (const float*)d_in[4];
    const float* b0  = (const float*)d_in[5];
    const float* W1  = (const float*)d_in[6];
    const float* as1 = (const float*)d_in[7];
    const float* ad1 = (const float*)d_in[8];
    const float* b1  = (const float*)d_in[9];
    const float* W2  = (const float*)d_in[10];
    const float* as2 = (const float*)d_in[11];
    const float* ad2 = (const float*)d_in[12];
    const float* b2  = (const float*)d_in[13];
    float* out = (float*)d_out;

    char* p = (char*)d_ws;
    int* deg    = (int*)p; p += 40000;
    int* cursor = (int*)p; p += 40000;
    int* off    = (int*)p; p += 40016;
    int* srcs   = (int*)p; p += 680000;
    float* hx   = (float*)p; p += 20480000;
    float* fA   = (float*)p; p += 20480000;
    float* fB   = (float*)p; p += 20480000;
    float* alsb = (float*)p; p += 320000;
    float* aldb = (float*)p; p += 320000;

    // CSR by dst (rebuilt every call; no cross-call state)
    zero_int<<<(NN + 255) / 256, 256, 0, stream>>>(deg, NN);
    hist_kernel<<<(ET + 255) / 256, 256, 0, stream>>>(ei, deg);
    scan_kernel<<<1, 1024, 0, stream>>>(deg, off, cursor);
    scatter_kernel<<<(ET + 255) / 256, 256, 0, stream>>>(ei, cursor, srcs);

    dim3 g0((NN + 63) / 64, HC / 64);
    // layer 0
    gemm_kernel<<<g0, 256, 0, stream>>>(x, W0, hx, NN, FIN, HC);
    attn_kernel<<<(NN + 3) / 4, 256, 0, stream>>>(hx, as0, ad0, alsb, aldb, HH, CC);
    aggregate_kernel<<<NN, 256, 0, stream>>>(hx, alsb, aldb, off, srcs, b0, fA, 1);
    // layer 1
    gemm_kernel<<<g0, 256, 0, stream>>>(fA, W1, hx, NN, HC, HC);
    attn_kernel<<<(NN + 3) / 4, 256, 0, stream>>>(hx, as1, ad1, alsb, aldb, HH, CC);
    aggregate_kernel<<<NN, 256, 0, stream>>>(hx, alsb, aldb, off, srcs, b1, fB, 1);
    // layer 2
    dim3 g2((NN + 63) / 64, 1);
    gemm_kernel<<<g2, 256, 0, stream>>>(fB, W2, hx, NN, HC, NCLS);
    attn_kernel<<<(NN + 3) / 4, 256, 0, stream>>>(hx, as2, ad2, alsb, aldb, 1, NCLS);
    aggregate2_kernel<<<NN, 64, 0, stream>>>(hx, alsb, aldb, off, srcs, b2, out);
}